// Round 1
// 516.143 us; speedup vs baseline: 1.0882x; 1.0882x over previous
//
#include <hip/hip_runtime.h>

// RoutedSelfAttention on MI355X.
// meanpool+cast -> router -> wcast (W^T bf16) -> MFMA GEMM qkv (2-phase dbuf pipeline,
// XCD-swizzled, cheap-RoPE epilogue, v written transposed)
// -> bf16 MFMA flash attention (128-row Q tiles, dbuf K/vT, xor-swizzled LDS, XCD-swizzled,
//    setprio around MFMA) -> MFMA GEMM out.

typedef __attribute__((ext_vector_type(8))) short bf16x8;
typedef __attribute__((ext_vector_type(4))) float f32x4;

typedef const __attribute__((address_space(1))) unsigned short* gas_t;
typedef __attribute__((address_space(3))) unsigned short* las_t;

#define OFF_PART   (0ull)            // [32][16][1024] f32 partial mean sums (2 MB)
#define OFF_ROUTES (2ull << 20)      // [32] int
#define OFF_XB     (3ull << 20)      // x bf16 [32][512][1024] (32 MB); reused as ctx
#define OFF_WT     (40ull << 20)     // W^T bf16 [4][8][1024][1024] (64 MB)
#define OFF_QKV    (112ull << 20)    // q,k [p][32][16][512][64]; vT [32][16][64][512] (96 MB)

__device__ __forceinline__ unsigned short f2bf(float f){
  unsigned int u = __float_as_uint(f);
  u += 0x7fffu + ((u >> 16) & 1u);          // RNE
  return (unsigned short)(u >> 16);
}

// ---------------- router (meanpool fused with bf16 cast) ----------------

__global__ void meanpool_kernel(const float* __restrict__ x, float* __restrict__ part,
                                unsigned short* __restrict__ xb){
  const int b = blockIdx.x, lc = blockIdx.y, t = threadIdx.x;
  const size_t base = ((size_t)b*512 + lc*32)*1024;
  const float* xs = x + base;
  unsigned short* xo = xb + base;
  float a0=0.f, a1=0.f, a2=0.f, a3=0.f;
  for (int l = 0; l < 32; ++l){
    const float* row = xs + l*1024;
    unsigned short* orow = xo + l*1024;
    const float v0 = row[t], v1 = row[t+256], v2 = row[t+512], v3 = row[t+768];
    a0 += v0; a1 += v1; a2 += v2; a3 += v3;
    orow[t] = f2bf(v0); orow[t+256] = f2bf(v1); orow[t+512] = f2bf(v2); orow[t+768] = f2bf(v3);
  }
  float* o = part + ((size_t)b*16 + lc)*1024;
  o[t] = a0; o[t+256] = a1; o[t+512] = a2; o[t+768] = a3;
}

__global__ void router_kernel(const float* __restrict__ part,
                              const float* __restrict__ rw,
                              const float* __restrict__ rbias,
                              float* __restrict__ probs,
                              int* __restrict__ routes){
  const int b = blockIdx.x, t = threadIdx.x;
  __shared__ float xbar[1024];
  __shared__ float red[256*8];
  #pragma unroll
  for (int k = 0; k < 4; ++k){
    const int d = t + k*256;
    float s = 0.f;
    for (int lc = 0; lc < 16; ++lc) s += part[((size_t)b*16 + lc)*1024 + d];
    xbar[d] = s * (1.0f/512.0f);
  }
  __syncthreads();
  float p[8] = {0.f,0.f,0.f,0.f,0.f,0.f,0.f,0.f};
  #pragma unroll
  for (int k = 0; k < 4; ++k){
    const int d = t + k*256;
    const float xv = xbar[d];
    #pragma unroll
    for (int e = 0; e < 8; ++e) p[e] = fmaf(xv, rw[d*8 + e], p[e]);
  }
  #pragma unroll
  for (int e = 0; e < 8; ++e) red[t*8 + e] = p[e];
  __syncthreads();
  for (int s2 = 128; s2 > 0; s2 >>= 1){
    if (t < s2){
      #pragma unroll
      for (int e = 0; e < 8; ++e) red[t*8 + e] += red[(t + s2)*8 + e];
    }
    __syncthreads();
  }
  if (t == 0){
    float lg[8], mx = -3e38f; int am = 0;
    #pragma unroll
    for (int e = 0; e < 8; ++e){
      lg[e] = red[e] + rbias[e];
      if (lg[e] > mx){ mx = lg[e]; am = e; }
    }
    float sum = 0.f, ex[8];
    #pragma unroll
    for (int e = 0; e < 8; ++e){ ex[e] = __expf(lg[e] - mx); sum += ex[e]; }
    const float inv = 1.0f / sum;
    #pragma unroll
    for (int e = 0; e < 8; ++e) probs[b*8 + e] = ex[e] * inv;
    routes[b] = am;
  }
}

// ---------------- weight transpose-cast ----------------

__global__ void wcast_kernel(const float* __restrict__ W, unsigned short* __restrict__ Wt){
  __shared__ float tile[32][33];
  const int mtx = blockIdx.z;
  const float* Wm = W + (size_t)mtx*1024*1024;
  unsigned short* Wo = Wt + (size_t)mtx*1024*1024;
  const int t = threadIdx.x;
  const int c = t & 31, r0 = t >> 5;
  const int gx = blockIdx.x*32, gy = blockIdx.y*32;
  #pragma unroll
  for (int k = 0; k < 4; ++k){
    const int r = r0 + k*8;
    tile[r][c] = Wm[(size_t)(gy + r)*1024 + gx + c];
  }
  __syncthreads();
  #pragma unroll
  for (int k = 0; k < 4; ++k){
    const int r = r0 + k*8;
    Wo[(size_t)(gx + r)*1024 + gy + c] = f2bf(tile[c][r]);
  }
}

// ---------------- bf16 MFMA GEMM (128x128 tile, BK=32, xor-swizzled LDS) ----------------
// 2-phase pipeline: double-buffered LDS, issue next K-step's global_load_lds right after
// the (single) per-iter barrier, compute current; XCD-contiguous slice swizzle.
// MODE 0: A=xb[b], W=Wt[p*8+route]; p<2: RoPE -> q/k [p][b][h][l][d]; p==2: vT [b][h][d][l]
// MODE 1: A=ctx[b], W=Wt_o[route]; -> d_out fp32

template<int MODE>
__global__ __launch_bounds__(256, 2) void gemm_kernel(
    const unsigned short* __restrict__ A,
    const unsigned short* __restrict__ Wt,
    const int* __restrict__ routes,
    unsigned short* __restrict__ qkvout,
    float* __restrict__ outf)
{
  __shared__ __align__(16) unsigned short As[2][128*32];
  __shared__ __align__(16) unsigned short Bs[2][128*32];

  // XCD-contiguous swizzle: physical XCD = dispatch_index % 8; relabel so each XCD owns
  // a contiguous run of slices (same-slice blocks share A/B panels in its L2).
  // z ordering: the 3 projections of one batch are adjacent (share the 1MB A panel).
  int wg = blockIdx.x + (blockIdx.y << 3) + (blockIdx.z << 5);
  wg = (wg & 7) * ((MODE == 0) ? 384 : 128) + (wg >> 3);
  const int z   = wg >> 5;
  const int rem = wg & 31;
  const int m0  = (rem >> 3) * 128;
  const int n0  = (rem & 7) * 128;
  const int b = (MODE == 0) ? (z / 3) : z;
  const int p = (MODE == 0) ? (z - b*3) : 0;

  const int route = routes[b];
  const unsigned short* Ab = A + (size_t)b*512*1024;
  const unsigned short* Wb = Wt + (size_t)((MODE == 0) ? (p*8 + route) : route)*1024*1024;
  const int t = threadIdx.x;
  const int lane = t & 63;
  const int wave = t >> 6;
  const int wm = (wave >> 1) * 64;
  const int wn = (wave & 1) * 64;
  const int quad = lane >> 4;
  const int ln = lane & 15;

  f32x4 acc[4][4] = {};

  // staging: unit u -> row u>>2, chunk (u&3); fetch global chunk (u&3)^((row>>1)&3)
  const int u0 = t, u1 = t + 256;
  const int r0s = u0 >> 2, c0s = (u0 & 3) ^ ((r0s >> 1) & 3);
  const int r1s = u1 >> 2, c1s = (u1 & 3) ^ ((r1s >> 1) & 3);
  const unsigned short* gA0 = Ab + (size_t)(m0 + r0s)*1024 + c0s*8;
  const unsigned short* gA1 = Ab + (size_t)(m0 + r1s)*1024 + c1s*8;
  const unsigned short* gB0 = Wb + (size_t)(n0 + r0s)*1024 + c0s*8;
  const unsigned short* gB1 = Wb + (size_t)(n0 + r1s)*1024 + c1s*8;
  las_t lA0 = (las_t)(&As[0][0] + u0*8), lA1 = (las_t)(&As[0][0] + u1*8);
  las_t lB0 = (las_t)(&Bs[0][0] + u0*8), lB1 = (las_t)(&Bs[0][0] + u1*8);

  // reader: row = w?+i*16+ln, chunk quad -> slot quad^((ln>>1)&3)  (wm/wn/i*16 vanish mod 4)
  const int swz = (quad ^ ((ln >> 1) & 3)) * 8;
  int offA[4], offB[4];
  #pragma unroll
  for (int i = 0; i < 4; ++i){
    offA[i] = (wm + i*16 + ln)*32 + swz;
    offB[i] = (wn + i*16 + ln)*32 + swz;
  }

#define STAGE(buf, kk) do { \
    const int boff_ = (buf)*4096; \
    __builtin_amdgcn_global_load_lds((gas_t)(gA0 + (kk)), lA0 + boff_, 16, 0, 0); \
    __builtin_amdgcn_global_load_lds((gas_t)(gA1 + (kk)), lA1 + boff_, 16, 0, 0); \
    __builtin_amdgcn_global_load_lds((gas_t)(gB0 + (kk)), lB0 + boff_, 16, 0, 0); \
    __builtin_amdgcn_global_load_lds((gas_t)(gB1 + (kk)), lB1 + boff_, 16, 0, 0); \
  } while (0)

  STAGE(0, 0);
  for (int k0 = 0; k0 < 1024; k0 += 32){
    const int cur = (k0 >> 5) & 1;
    __syncthreads();                       // drains this buf's loads + prev iter's ds_reads
    if (k0 + 32 < 1024) STAGE(cur ^ 1, k0 + 32);   // hidden under this iter's compute
    const unsigned short* Al = &As[cur][0];
    const unsigned short* Bl = &Bs[cur][0];
    bf16x8 av[4], bv[4];
    #pragma unroll
    for (int i = 0; i < 4; ++i){
      av[i] = *(const bf16x8*)(Al + offA[i]);
      bv[i] = *(const bf16x8*)(Bl + offB[i]);
    }
    #pragma unroll
    for (int i = 0; i < 4; ++i)
      #pragma unroll
      for (int j = 0; j < 4; ++j)
        acc[i][j] = __builtin_amdgcn_mfma_f32_16x16x32_bf16(av[i], bv[j], acc[i][j], 0, 0, 0);
  }
#undef STAGE

  if (MODE == 0){
    const size_t PSZ = (size_t)32*16*512*64;
    if (p < 2){
      // RoPE epilogue: 20 sincos instead of 64 — one base angle per (i,j), then
      // angle-addition rotation by invf across the 4 consecutive positions r.
      #pragma unroll
      for (int j = 0; j < 4; ++j){
        const int e  = n0 + wn + j*16 + ln;
        const int h  = e >> 6;
        const int eh = e & 63;
        const float invf = exp2f(-0.41524101f * (float)(eh >> 1)); // 10000^(-2i/64)
        float s1, c1; __sincosf(invf, &s1, &c1);
        unsigned short* outp = qkvout + ((((size_t)p*32 + b)*16 + h)*512)*64 + eh;
        const int l0 = m0 + wm + quad*4;
        #pragma unroll
        for (int i = 0; i < 4; ++i){
          float sn, cs;
          __sincosf((float)(l0 + i*16) * invf, &sn, &cs);
          #pragma unroll
          for (int r = 0; r < 4; ++r){
            const int l = l0 + i*16 + r;
            const float own = acc[i][j][r];
            const float par = __shfl_xor(own, 1, 64);
            const float v = (e & 1) ? fmaf(own, cs, par*sn) : fmaf(own, cs, -par*sn);
            outp[(size_t)l*64] = f2bf(v);
            const float nc = cs*c1 - sn*s1;     // rotate angle by +invf
            const float ns = sn*c1 + cs*s1;
            cs = nc; sn = ns;
          }
        }
      }
    } else {
      // vT[b][h][d][l]: pack 4 consecutive l (r=0..3) into one 8B store
      #pragma unroll
      for (int j = 0; j < 4; ++j){
        const int e  = n0 + wn + j*16 + ln;
        const int h  = e >> 6;
        const int eh = e & 63;
        unsigned short* outp = qkvout + 2*PSZ + (((size_t)b*16 + h)*64 + eh)*512;
        #pragma unroll
        for (int i = 0; i < 4; ++i){
          const int l0 = m0 + wm + i*16 + quad*4;
          ushort4 pk;
          pk.x = f2bf(acc[i][j][0]); pk.y = f2bf(acc[i][j][1]);
          pk.z = f2bf(acc[i][j][2]); pk.w = f2bf(acc[i][j][3]);
          *(ushort4*)(outp + l0) = pk;
        }
      }
    }
  } else {
    #pragma unroll
    for (int j = 0; j < 4; ++j){
      const int e = n0 + wn + j*16 + ln;
      #pragma unroll
      for (int i = 0; i < 4; ++i){
        #pragma unroll
        for (int r = 0; r < 4; ++r){
          const int l = m0 + wm + i*16 + quad*4 + r;
          outf[((size_t)b*512 + l)*1024 + e] = acc[i][j][r];
        }
      }
    }
  }
}

// ---------------- bf16 MFMA flash attention, 128-row Q blocks ----------------
// Block=(qt128,h,b), 4 waves; wave owns rows {qt*128+rg*64+w*16 .. +15} for rg=0,1.
// Q in registers; K and vT double-buffered via global_load_lds (xor-swizzled, 8 chunks/row);
// one barrier per 64-key tile. P round-trip through wave-local LDS (stride 72, 2-way free).
// XCD swizzle co-locates the 4 qt-blocks of each (b,h) -> K/V L2 reuse.

#define PSTR 72

__global__ __launch_bounds__(256, 3) void attn_kernel(
    const unsigned short* __restrict__ qkv,
    unsigned short* __restrict__ ctx)
{
  __shared__ __align__(16) unsigned short Ks[2][64*64];
  __shared__ __align__(16) unsigned short Vts[2][64*64];
  __shared__ __align__(16) unsigned short Ps[4][32*PSTR];

  // grid (4,16,32): wg = qt + 4h + 64b; co-locate same-(b,h) qt blocks per XCD.
  int wg = blockIdx.x + (blockIdx.y << 2) + (blockIdx.z << 6);
  wg = (wg & 7) * 256 + (wg >> 3);
  const int b  = wg >> 6;
  const int h  = (wg >> 2) & 15;
  const int qt = wg & 3;

  const size_t HO  = (((size_t)b)*16 + h)*512*64;
  const size_t PSZ = (size_t)32*16*512*64;
  const unsigned short* Qg  = qkv + HO;
  const unsigned short* Kg  = qkv + PSZ + HO;
  const unsigned short* Vtg = qkv + 2*PSZ + HO;   // [d][l], row stride 512

  const int t    = threadIdx.x;
  const int lane = t & 63;
  const int wave = t >> 6;
  const int quad = lane >> 4;
  const int ln   = lane & 15;

  // staging: unit u -> row u>>3, chunk u&7; fetch global chunk (u&7)^(row&7)
  const int u0 = t, u1 = t + 256;
  const int kr0 = u0 >> 3, kc0 = (u0 & 7) ^ (kr0 & 7);
  const int kr1 = u1 >> 3, kc1 = (u1 & 7) ^ (kr1 & 7);

  // Q fragments (A-layout) straight from global
  bf16x8 aq[2][2];
  #pragma unroll
  for (int rg = 0; rg < 2; ++rg){
    const int row = qt*128 + rg*64 + wave*16 + ln;
    #pragma unroll
    for (int ks = 0; ks < 2; ++ks)
      aq[rg][ks] = *(const bf16x8*)(Qg + (size_t)row*64 + ks*32 + quad*8);
  }

  const int ktEnd = 2*qt + 1;

  // prefetch kt=0
  __builtin_amdgcn_global_load_lds((gas_t)(Kg  + kr0*64  + kc0*8), (las_t)(Ks[0]  + u0*8), 16,0,0);
  __builtin_amdgcn_global_load_lds((gas_t)(Kg  + kr1*64  + kc1*8), (las_t)(Ks[0]  + u1*8), 16,0,0);
  __builtin_amdgcn_global_load_lds((gas_t)(Vtg + kr0*512 + kc0*8), (las_t)(Vts[0] + u0*8), 16,0,0);
  __builtin_amdgcn_global_load_lds((gas_t)(Vtg + kr1*512 + kc1*8), (las_t)(Vts[0] + u1*8), 16,0,0);

  float m_r[2][4], l_r[2][4];
  #pragma unroll
  for (int rg = 0; rg < 2; ++rg)
    #pragma unroll
    for (int r = 0; r < 4; ++r){ m_r[rg][r] = -3e38f; l_r[rg][r] = 0.f; }
  f32x4 o[2][4] = {};

  const int swzl = ln & 7;            // reader xor (row&7 == ln&7 for rows kn*16+ln / dn*16+ln)
  unsigned short* Pw = Ps[wave];
  const int rowoff = wave*16 + quad*4;

  for (int kt = 0; kt <= ktEnd; ++kt){
    __syncthreads();                  // drains kt's loads; protects other buffer's readers
    if (kt < ktEnd){
      const unsigned short* Kn  = Kg + (kt+1)*4096;
      const int col = (kt+1)*64;
      unsigned short* kb = Ks[(kt+1)&1];
      unsigned short* vb = Vts[(kt+1)&1];
      __builtin_amdgcn_global_load_lds((gas_t)(Kn  + kr0*64 + kc0*8),        (las_t)(kb + u0*8), 16,0,0);
      __builtin_amdgcn_global_load_lds((gas_t)(Kn  + kr1*64 + kc1*8),        (las_t)(kb + u1*8), 16,0,0);
      __builtin_amdgcn_global_load_lds((gas_t)(Vtg + kr0*512 + col + kc0*8), (las_t)(vb + u0*8), 16,0,0);
      __builtin_amdgcn_global_load_lds((gas_t)(Vtg + kr1*512 + col + kc1*8), (las_t)(vb + u1*8), 16,0,0);
    }
    const unsigned short* ks_ = Ks[kt&1];
    const unsigned short* vt_ = Vts[kt&1];

    #pragma unroll
    for (int rg = 0; rg < 2; ++rg){
      if (rg == 0 && kt > 2*qt) continue;       // rg0 fully masked only at kt==ktEnd
      const bool diag = (kt == 2*qt + rg);

      f32x4 s[4] = {};
      __builtin_amdgcn_s_setprio(1);
      #pragma unroll
      for (int ks2 = 0; ks2 < 2; ++ks2){
        #pragma unroll
        for (int kn = 0; kn < 4; ++kn){
          const bf16x8 bk = *(const bf16x8*)(ks_ + (kn*16+ln)*64 + (((quad + ks2*4) ^ swzl))*8);
          s[kn] = __builtin_amdgcn_mfma_f32_16x16x32_bf16(aq[rg][ks2], bk, s[kn], 0, 0, 0);
        }
      }
      __builtin_amdgcn_s_setprio(0);

      float p[4][4], lm[4] = {-3e38f,-3e38f,-3e38f,-3e38f};
      #pragma unroll
      for (int kn = 0; kn < 4; ++kn){
        const int col = kn*16 + ln;
        #pragma unroll
        for (int r = 0; r < 4; ++r){
          float v = s[kn][r] * 0.125f;
          if (diag && col > rowoff + r) v = -1e9f;
          p[kn][r] = v;
          lm[r] = fmaxf(lm[r], v);
        }
      }
      #pragma unroll
      for (int off = 1; off < 16; off <<= 1)
        #pragma unroll
        for (int r = 0; r < 4; ++r)
          lm[r] = fmaxf(lm[r], __shfl_xor(lm[r], off, 64));
      float alpha[4], rsum[4];
      #pragma unroll
      for (int r = 0; r < 4; ++r){
        const float mn = fmaxf(m_r[rg][r], lm[r]);
        alpha[r] = __expf(m_r[rg][r] - mn);
        m_r[rg][r] = mn;
      }
      #pragma unroll
      for (int kn = 0; kn < 4; ++kn)
        #pragma unroll
        for (int r = 0; r < 4; ++r)
          p[kn][r] = __expf(p[kn][r] - m_r[rg][r]);
      #pragma unroll
      for (int r = 0; r < 4; ++r)
        rsum[r] = (p[0][r] + p[1][r]) + (p[2][r] + p[3][r]);
      #pragma unroll
      for (int off = 1; off < 16; off <<= 1)
        #pragma unroll
        for (int r = 0; r < 4; ++r)
          rsum[r] += __shfl_xor(rsum[r], off, 64);
      #pragma unroll
      for (int r = 0; r < 4; ++r) l_r[rg][r] = l_r[rg][r]*alpha[r] + rsum[r];
      #pragma unroll
      for (int dn = 0; dn < 4; ++dn)
        #pragma unroll
        for (int r = 0; r < 4; ++r)
          o[rg][dn][r] *= alpha[r];

      // P: C-layout -> wave-local LDS [row-in-rg 0..31][key], A-layout source
      #pragma unroll
      for (int kn = 0; kn < 4; ++kn)
        #pragma unroll
        for (int r = 0; r < 4; ++r)
          Pw[(rg*16 + quad*4 + r)*PSTR + kn*16 + ln] = f2bf(p[kn][r]);

      __builtin_amdgcn_s_setprio(1);
      #pragma unroll
      for (int ks2 = 0; ks2 < 2; ++ks2){
        const bf16x8 ap = *(const bf16x8*)(Pw + (rg*16 + ln)*PSTR + quad*8 + ks2*32);
        #pragma unroll
        for (int dn = 0; dn < 4; ++dn){
          const bf16x8 bv = *(const bf16x8*)(vt_ + (dn*16+ln)*64 + (((quad + ks2*4) ^ swzl))*8);
          o[rg][dn] = __builtin_amdgcn_mfma_f32_16x16x32_bf16(ap, bv, o[rg][dn], 0, 0, 0);
        }
      }
      __builtin_amdgcn_s_setprio(0);
    }
  }

  #pragma unroll
  for (int rg = 0; rg < 2; ++rg){
    #pragma unroll
    for (int r = 0; r < 4; ++r){
      const float inv = 1.0f / l_r[rg][r];
      const int row = qt*128 + rg*64 + wave*16 + quad*4 + r;
      unsigned short* op = ctx + ((size_t)b*512 + row)*1024 + h*64 + ln;
      #pragma unroll
      for (int dn = 0; dn < 4; ++dn)
        op[dn*16] = f2bf(o[rg][dn][r] * inv);
    }
  }
}

// ---------------- launch ----------------

extern "C" void kernel_launch(void* const* d_in, const int* in_sizes, int n_in,
                              void* d_out, int out_size, void* d_ws, size_t ws_size,
                              hipStream_t stream) {
  const float* x     = (const float*)d_in[0];
  const float* qw    = (const float*)d_in[1];
  const float* kw    = (const float*)d_in[2];
  const float* vw    = (const float*)d_in[3];
  const float* ow    = (const float*)d_in[4];
  const float* rw    = (const float*)d_in[5];
  const float* rbias = (const float*)d_in[6];
  float* out = (float*)d_out;
  char* ws = (char*)d_ws;

  float* part            = (float*)(ws + OFF_PART);
  int* routes            = (int*)(ws + OFF_ROUTES);
  unsigned short* xb     = (unsigned short*)(ws + OFF_XB);
  unsigned short* wt     = (unsigned short*)(ws + OFF_WT);
  unsigned short* qkvbuf = (unsigned short*)(ws + OFF_QKV);
  unsigned short* ctx    = xb;
  float* probs = out + (size_t)32*512*1024;

  meanpool_kernel<<<dim3(32, 16), 256, 0, stream>>>(x, part, xb);
  router_kernel<<<32, 256, 0, stream>>>(part, rw, rbias, probs, routes);
  wcast_kernel<<<dim3(32, 32, 8), 256, 0, stream>>>(qw, wt);
  wcast_kernel<<<dim3(32, 32, 8), 256, 0, stream>>>(kw, wt + (size_t)8*1024*1024);
  wcast_kernel<<<dim3(32, 32, 8), 256, 0, stream>>>(vw, wt + (size_t)16*1024*1024);
  wcast_kernel<<<dim3(32, 32, 8), 256, 0, stream>>>(ow, wt + (size_t)24*1024*1024);
  gemm_kernel<0><<<dim3(8, 4, 96), 256, 0, stream>>>(xb, wt, routes, qkvbuf, nullptr);
  attn_kernel<<<dim3(4, 16, 32), 256, 0, stream>>>(qkvbuf, ctx);
  gemm_kernel<1><<<dim3(8, 4, 32), 256, 0, stream>>>(ctx, wt + (size_t)24*1024*1024, routes,
                                                     nullptr, out);
}